// Round 2
// baseline (34.436 us; speedup 1.0000x reference)
//
#include <hip/hip_runtime.h>

#define B_N 2048
#define E_N 64
#define D_N 512
#define O_N 512
#define ON  64    // output columns per block
#define MC  64    // sample rows per chunk (covers n<=64 in one weight pass)
#define XS_LD 520 // padded LDS row stride in bf16 elems

typedef __bf16 bf16x8 __attribute__((ext_vector_type(8)));
typedef float  f32x4  __attribute__((ext_vector_type(4)));

__device__ __forceinline__ unsigned short f2bf(float f) {
  unsigned int u = __float_as_uint(f);
  u = (u + 0x7FFFu + ((u >> 16) & 1u)) >> 16;  // RNE
  return (unsigned short)u;
}
__device__ __forceinline__ unsigned short u2bf(unsigned int u) {
  u = (u + 0x7FFFu + ((u >> 16) & 1u)) >> 16;
  return (unsigned short)u;
}

__global__ void bucket_kernel(const int* __restrict__ opt,
                              int* __restrict__ cnt,
                              int* __restrict__ list) {
  __shared__ int scnt[E_N];
  const int t = threadIdx.x;           // 1024 threads
  if (t < E_N) scnt[t] = 0;
  __syncthreads();
#pragma unroll
  for (int i = 0; i < B_N / 1024; ++i) {
    int b = t + i * 1024;
    int e = opt[b];
    int slot = atomicAdd(&scnt[e], 1);
    list[e * B_N + slot] = b;
  }
  __syncthreads();
  if (t < E_N) cnt[t] = scnt[t];
}

// Grouped GEMM: block = (expert, 64-col o-tile). 512 threads = 8 waves =
// 2 m-groups (32 rows each) x 4 col-groups (16 cols each). Weight B-fragments
// are software-pipelined: raw uint dwords for step k+32 are issued before
// converting/MFMAing step k (2x-unrolled ping-pong, no copies), so each wave
// keeps 8-16 global loads in flight -> latency-bound becomes BW-bound.
__global__ __launch_bounds__(512)
void gemm_kernel(const float* __restrict__ x,
                 const float* __restrict__ w,
                 const float* __restrict__ bias,
                 const int* __restrict__ cnt,
                 const int* __restrict__ list,
                 float* __restrict__ out) {
  __shared__ unsigned short xs[MC * XS_LD];   // 64 x 520 bf16 = 65 KB

  const int e    = blockIdx.x;
  const int o0   = blockIdx.y * ON;
  const int t    = threadIdx.x;
  const int lane = t & 63;
  const int wave = t >> 6;
  const int wc   = wave & 3;   // col-group
  const int wg   = wave >> 2;  // m-group
  const int n    = cnt[e];
  if (n == 0) return;          // block-uniform

  const float* wexp = w + (size_t)e * D_N * O_N;
  const int m_in = lane & 15;  // A-row / B-col / D-col within 16
  const int g    = lane >> 4;  // k-group 0..3
  const int col  = o0 + wc * 16 + m_in;
  const float bval = bias[e * O_N + col];
  const int* mylist = list + e * B_N;
  const int arow0 = (wg * 32 + m_in) * XS_LD;

  for (int m0 = 0; m0 < n; m0 += MC) {
    __syncthreads();   // protect xs from readers of previous chunk
    // Stage MC rows x 512 cols fp32 -> bf16 LDS: 8192 float4 over 512 threads.
#pragma unroll
    for (int i = 0; i < 16; ++i) {
      int idx = t + i * 512;
      int row = idx >> 7;       // 128 float4 per row
      int c4  = idx & 127;
      int s   = m0 + row;
      ushort4 v = make_ushort4(0, 0, 0, 0);
      if (s < n) {
        const float4 xv = *reinterpret_cast<const float4*>(x + (size_t)mylist[s] * D_N + c4 * 4);
        v = make_ushort4(f2bf(xv.x), f2bf(xv.y), f2bf(xv.z), f2bf(xv.w));
      }
      *reinterpret_cast<ushort4*>(&xs[row * XS_LD + c4 * 4]) = v;
    }
    __syncthreads();

    f32x4 acc0 = {0.f, 0.f, 0.f, 0.f};
    f32x4 acc1 = {0.f, 0.f, 0.f, 0.f};

    unsigned bu[8], bn[8];
    // prologue: issue loads for k0 = 0
    {
      const float* wp = wexp + (size_t)(g * 8) * O_N + col;
#pragma unroll
      for (int j = 0; j < 8; ++j) bu[j] = __float_as_uint(wp[(size_t)j * O_N]);
    }

    for (int k0 = 0; k0 < D_N; k0 += 64) {
      // ---- issue loads for k0+32 ----
      {
        const float* wp = wexp + (size_t)(k0 + 32 + g * 8) * O_N + col;
#pragma unroll
        for (int j = 0; j < 8; ++j) bn[j] = __float_as_uint(wp[(size_t)j * O_N]);
      }
      // ---- compute step k0 with bu ----
      {
        const int kb = arow0 + k0 + g * 8;
        union { uint4 u; bf16x8 v; } a0, a1;
        a0.u = *reinterpret_cast<const uint4*>(&xs[kb]);
        a1.u = *reinterpret_cast<const uint4*>(&xs[kb + 16 * XS_LD]);
        union { unsigned short us[8]; bf16x8 v; } bf;
#pragma unroll
        for (int j = 0; j < 8; ++j) bf.us[j] = u2bf(bu[j]);
        acc0 = __builtin_amdgcn_mfma_f32_16x16x32_bf16(a0.v, bf.v, acc0, 0, 0, 0);
        acc1 = __builtin_amdgcn_mfma_f32_16x16x32_bf16(a1.v, bf.v, acc1, 0, 0, 0);
      }
      // ---- issue loads for k0+64 (wraps to 0 on last iter; valid addrs, unused) ----
      {
        const float* wp = wexp + (size_t)(((k0 + 64) & (D_N - 1)) + g * 8) * O_N + col;
#pragma unroll
        for (int j = 0; j < 8; ++j) bu[j] = __float_as_uint(wp[(size_t)j * O_N]);
      }
      // ---- compute step k0+32 with bn ----
      {
        const int kb = arow0 + k0 + 32 + g * 8;
        union { uint4 u; bf16x8 v; } a0, a1;
        a0.u = *reinterpret_cast<const uint4*>(&xs[kb]);
        a1.u = *reinterpret_cast<const uint4*>(&xs[kb + 16 * XS_LD]);
        union { unsigned short us[8]; bf16x8 v; } bf;
#pragma unroll
        for (int j = 0; j < 8; ++j) bf.us[j] = u2bf(bn[j]);
        acc0 = __builtin_amdgcn_mfma_f32_16x16x32_bf16(a0.v, bf.v, acc0, 0, 0, 0);
        acc1 = __builtin_amdgcn_mfma_f32_16x16x32_bf16(a1.v, bf.v, acc1, 0, 0, 0);
      }
    }

    // D layout (m89-verified): col = lane&15, row = (lane>>4)*4 + reg
#pragma unroll
    for (int r = 0; r < 4; ++r) {
      int sl = wg * 32 + g * 4 + r;
      int s  = m0 + sl;
      if (s < n)      out[(size_t)mylist[s]  * O_N + col] = acc0[r] + bval;
      int s2 = m0 + sl + 16;
      if (s2 < n)     out[(size_t)mylist[s2] * O_N + col] = acc1[r] + bval;
    }
  }
}

extern "C" void kernel_launch(void* const* d_in, const int* in_sizes, int n_in,
                              void* d_out, int out_size, void* d_ws, size_t ws_size,
                              hipStream_t stream) {
  const float* x      = (const float*)d_in[0];
  const int*   option = (const int*)d_in[1];
  const float* weight = (const float*)d_in[2];
  const float* bias   = (const float*)d_in[3];
  float* out = (float*)d_out;

  int* cnt  = (int*)d_ws;                       // 64 ints
  int* list = (int*)((char*)d_ws + 256);        // 64 * 2048 ints

  bucket_kernel<<<1, 1024, 0, stream>>>(option, cnt, list);
  gemm_kernel<<<dim3(E_N, O_N / ON), 512, 0, stream>>>(x, weight, bias, cnt, list, out);
}

// Round 3
// 33.176 us; speedup vs baseline: 1.0380x; 1.0380x over previous
//
#include <hip/hip_runtime.h>

#define B_N 2048
#define E_N 64
#define D_N 512
#define O_N 512
#define ON  64   // output cols per block
#define MC  64   // sample rows per chunk
#define NT  16   // k-steps of 32

typedef __bf16 bf16x8 __attribute__((ext_vector_type(8)));
typedef float  f32x4  __attribute__((ext_vector_type(4)));

__device__ __forceinline__ unsigned short f2bf(float f) {
  unsigned int u = __float_as_uint(f);
  u = (u + 0x7FFFu + ((u >> 16) & 1u)) >> 16;  // RNE
  return (unsigned short)u;
}

// 8 blocks x 256: global-atomic bucketing. List order is nondeterministic but
// the OUTPUT is order-invariant (each out row = its own full dot product).
__global__ __launch_bounds__(256)
void bucket_kernel(const int* __restrict__ opt, int* __restrict__ cnt,
                   int* __restrict__ list) {
  int b = blockIdx.x * 256 + threadIdx.x;
  int e = opt[b];
  int slot = atomicAdd(&cnt[e], 1);
  list[e * B_N + slot] = b;
}

__device__ __forceinline__ void step_compute(
    const unsigned short* __restrict__ xs, const float* __restrict__ wsp,
    int kt, int g, int col64, int r0, int r1, f32x4& acc0, f32x4& acc1) {
  const int kb = kt * 32 + g * 8;
  const int key = (r0 & 7) << 3;              // r1&7 == r0&7 (r1 = r0+16)
  union { uint4 u; bf16x8 v; } a0, a1;
  a0.u = *reinterpret_cast<const uint4*>(&xs[r0 * 512 + ((kb ^ key))]);
  a1.u = *reinterpret_cast<const uint4*>(&xs[r1 * 512 + ((kb ^ key))]);
  union { unsigned short us[8]; bf16x8 v; } bf_;
  const int csw = col64 ^ (g << 4);           // read-side swizzle (matches DMA source swizzle)
#pragma unroll
  for (int j = 0; j < 8; ++j) bf_.us[j] = f2bf(wsp[(g * 8 + j) * 64 + csw]);
  acc0 = __builtin_amdgcn_mfma_f32_16x16x32_bf16(a0.v, bf_.v, acc0, 0, 0, 0);
  acc1 = __builtin_amdgcn_mfma_f32_16x16x32_bf16(a1.v, bf_.v, acc1, 0, 0, 0);
}

// One global_load_lds_dwordx4 per wave per 32-k tile: instr = wave covers
// k-rows 4*wave..4*wave+3, lane i -> dest bytes [i*16, i*16+16) (linear, m104).
// Source col pre-swizzled with ((krow>>3)&3)<<4 so the read side's XOR undoes it.
#define DMA_W(KT, WSBUF) do {                                                  \
    const float* _src = wexp + (size_t)((KT) * 32 + dk) * O_N + o0 + scol;     \
    __builtin_amdgcn_global_load_lds(                                          \
        (const __attribute__((address_space(1))) void*)_src,                   \
        (__attribute__((address_space(3))) void*)&WSBUF[wave * 256], 16, 0, 0);\
  } while (0)

#define WAIT1_BAR() asm volatile("s_waitcnt vmcnt(1)\ns_barrier" ::: "memory")
#define WAIT0_BAR() asm volatile("s_waitcnt vmcnt(0)\ns_barrier" ::: "memory")
#define LGKM_BAR()  asm volatile("s_waitcnt lgkmcnt(0)\ns_barrier" ::: "memory")

__global__ __launch_bounds__(512)
void gemm_kernel(const float* __restrict__ x, const float* __restrict__ w,
                 const float* __restrict__ bias, const int* __restrict__ cnt,
                 const int* __restrict__ list, float* __restrict__ out) {
  __shared__ unsigned short xs[MC * 512];  // 64 KB, XOR-swizzled (us ^= (row&7)<<3)
  __shared__ float wsA[32 * 64];           // 8 KB fp32 weight tile (double buffer)
  __shared__ float wsB[32 * 64];           // 8 KB

  const int e    = blockIdx.x;
  const int o0   = blockIdx.y * ON;
  const int t    = threadIdx.x;
  const int lane = t & 63;
  const int wave = t >> 6;
  const int wc   = wave & 3;   // col-group
  const int wg   = wave >> 2;  // m-group
  const int n    = cnt[e];
  if (n == 0) return;

  const float* wexp = w + (size_t)e * D_N * O_N;
  const int m_in  = lane & 15;
  const int g     = lane >> 4;
  const int col64 = wc * 16 + m_in;
  const float bval = bias[e * O_N + o0 + col64];
  const int* mylist = list + e * B_N;
  const int r0 = wg * 32 + m_in;
  const int r1 = r0 + 16;

  // DMA per-lane source constants (instr id = wave)
  const int dk   = 4 * wave + (lane >> 4);            // within-tile k-row
  const int skey = ((dk >> 3) & 3) << 4;
  const int scol = ((lane & 15) * 4) ^ skey;          // pre-swizzled source col

  for (int m0 = 0; m0 < n; m0 += MC) {
    __syncthreads();              // full drain; protects xs/ws across chunks
    DMA_W(0, wsA);                // overlap tile-0 DMA with x staging
    // Stage MC x 512 fp32 -> bf16 LDS (swizzled): 8192 float4 over 512 threads.
#pragma unroll
    for (int i = 0; i < 16; ++i) {
      int idx = t + i * 512;
      int row = idx >> 7;
      int c4  = idx & 127;
      int s   = m0 + row;
      ushort4 v = make_ushort4(0, 0, 0, 0);
      if (s < n) {
        const float4 xv = *reinterpret_cast<const float4*>(x + (size_t)mylist[s] * D_N + c4 * 4);
        v = make_ushort4(f2bf(xv.x), f2bf(xv.y), f2bf(xv.z), f2bf(xv.w));
      }
      *reinterpret_cast<ushort4*>(&xs[row * 512 + ((c4 * 4) ^ ((row & 7) << 3))]) = v;
    }
    __syncthreads();              // also drains tile-0 DMA (vmcnt(0))

    f32x4 acc0 = {0.f, 0.f, 0.f, 0.f};
    f32x4 acc1 = {0.f, 0.f, 0.f, 0.f};

#pragma unroll 1
    for (int kt = 0; kt < NT; kt += 2) {
      DMA_W(kt + 1, wsB);
      WAIT1_BAR();                          // tile kt landed; kt+1 in flight
      step_compute(xs, wsA, kt, g, col64, r0, r1, acc0, acc1);
      LGKM_BAR();                           // all waves done reading wsA
      if (kt + 2 < NT) { DMA_W(kt + 2, wsA); WAIT1_BAR(); }
      else             { WAIT0_BAR(); }
      step_compute(xs, wsB, kt + 1, g, col64, r0, r1, acc0, acc1);
      LGKM_BAR();                           // all waves done reading wsB
    }

    // D layout (m89-verified): col = lane&15, row = (lane>>4)*4 + reg
#pragma unroll
    for (int r = 0; r < 4; ++r) {
      int sl = wg * 32 + g * 4 + r;
      int s  = m0 + sl;
      if (s < n)  out[(size_t)mylist[s]  * O_N + o0 + col64] = acc0[r] + bval;
      int s2 = m0 + sl + 16;
      if (s2 < n) out[(size_t)mylist[s2] * O_N + o0 + col64] = acc1[r] + bval;
    }
  }
}

extern "C" void kernel_launch(void* const* d_in, const int* in_sizes, int n_in,
                              void* d_out, int out_size, void* d_ws, size_t ws_size,
                              hipStream_t stream) {
  const float* x      = (const float*)d_in[0];
  const int*   option = (const int*)d_in[1];
  const float* weight = (const float*)d_in[2];
  const float* bias   = (const float*)d_in[3];
  float* out = (float*)d_out;

  int* cnt  = (int*)d_ws;                    // 64 ints
  int* list = (int*)((char*)d_ws + 256);     // 64 * 2048 ints

  hipMemsetAsync(cnt, 0, E_N * sizeof(int), stream);
  bucket_kernel<<<B_N / 256, 256, 0, stream>>>(option, cnt, list);
  gemm_kernel<<<dim3(E_N, O_N / ON), 512, 0, stream>>>(x, weight, bias, cnt, list, out);
}